// Round 1
// baseline (437.930 us; speedup 1.0000x reference)
//
#include <hip/hip_runtime.h>

// Inverse 2D Haar DWT (pywt idwt2, 'haar').
// Input:  ll/lh/hl/hh, each (B,C,H,W) = (4,64,256,256) fp32.
// Output: (B,C,2H,2W) fp32.
// Per input coeff (h,w):
//   out[2h,  2w]   = (ll+lh+hl+hh)*0.5   (a)
//   out[2h,  2w+1] = (ll+lh-hl-hh)*0.5   (b)
//   out[2h+1,2w]   = (ll-lh+hl-hh)*0.5   (c)
//   out[2h+1,2w+1] = (ll-lh-hl+hh)*0.5   (d)
//
// One thread handles 4 consecutive input columns -> 4 float4 loads,
// 4 float4 stores (2 per output row). All accesses 16B-coalesced.

#define W_IN 256           // input width
#define H_IN 256           // input height
#define GPR 64             // float4 groups per input row (W_IN/4)
#define OUT_ROW_F4 128     // output row length in float4 (2*W_IN/4)

__global__ __launch_bounds__(256) void idwt2_haar_kernel(
    const float* __restrict__ ll, const float* __restrict__ lh,
    const float* __restrict__ hl, const float* __restrict__ hh,
    float* __restrict__ out, int n_groups) {
    int idx = blockIdx.x * blockDim.x + threadIdx.x;
    if (idx >= n_groups) return;

    int g       = idx & (GPR - 1);   // float4 group within input row
    int rowflat = idx >> 6;          // flat input row index in [0, B*C*H)
    int r       = rowflat & (H_IN - 1);  // row within image
    int img     = rowflat >> 8;          // image index in [0, B*C)

    const float4 vll = ((const float4*)ll)[idx];
    const float4 vlh = ((const float4*)lh)[idx];
    const float4 vhl = ((const float4*)hl)[idx];
    const float4 vhh = ((const float4*)hh)[idx];

    float4 r0a, r0b, r1a, r1b;

    // lane 0
    {
        float s01 = vll.x + vlh.x, d01 = vll.x - vlh.x;
        float s23 = vhl.x + vhh.x, d23 = vhl.x - vhh.x;
        r0a.x = 0.5f * (s01 + s23);  // a0
        r0a.y = 0.5f * (s01 - s23);  // b0
        r1a.x = 0.5f * (d01 + d23);  // c0
        r1a.y = 0.5f * (d01 - d23);  // d0
    }
    // lane 1
    {
        float s01 = vll.y + vlh.y, d01 = vll.y - vlh.y;
        float s23 = vhl.y + vhh.y, d23 = vhl.y - vhh.y;
        r0a.z = 0.5f * (s01 + s23);  // a1
        r0a.w = 0.5f * (s01 - s23);  // b1
        r1a.z = 0.5f * (d01 + d23);  // c1
        r1a.w = 0.5f * (d01 - d23);  // d1
    }
    // lane 2
    {
        float s01 = vll.z + vlh.z, d01 = vll.z - vlh.z;
        float s23 = vhl.z + vhh.z, d23 = vhl.z - vhh.z;
        r0b.x = 0.5f * (s01 + s23);  // a2
        r0b.y = 0.5f * (s01 - s23);  // b2
        r1b.x = 0.5f * (d01 + d23);  // c2
        r1b.y = 0.5f * (d01 - d23);  // d2
    }
    // lane 3
    {
        float s01 = vll.w + vlh.w, d01 = vll.w - vlh.w;
        float s23 = vhl.w + vhh.w, d23 = vhl.w - vhh.w;
        r0b.z = 0.5f * (s01 + s23);  // a3
        r0b.w = 0.5f * (s01 - s23);  // b3
        r1b.z = 0.5f * (d01 + d23);  // c3
        r1b.w = 0.5f * (d01 - d23);  // d3
    }

    // Output rows (flat, in units of float4):
    // even row = img*(2*H_IN) + 2*r, odd row = +1
    int out_row0 = (img << 9) + (r << 1);        // img*512 + 2r
    long long base0 = (long long)out_row0 * OUT_ROW_F4 + (g << 1);
    long long base1 = base0 + OUT_ROW_F4;

    float4* out4 = (float4*)out;
    out4[base0]     = r0a;
    out4[base0 + 1] = r0b;
    out4[base1]     = r1a;
    out4[base1 + 1] = r1b;
}

extern "C" void kernel_launch(void* const* d_in, const int* in_sizes, int n_in,
                              void* d_out, int out_size, void* d_ws, size_t ws_size,
                              hipStream_t stream) {
    const float* ll = (const float*)d_in[0];
    const float* lh = (const float*)d_in[1];
    const float* hl = (const float*)d_in[2];
    const float* hh = (const float*)d_in[3];
    float* out = (float*)d_out;

    int n = in_sizes[0];           // 16,777,216 elements per input
    int n_groups = n / 4;          // 4,194,304 float4 groups
    int block = 256;
    int grid = (n_groups + block - 1) / block;

    idwt2_haar_kernel<<<grid, block, 0, stream>>>(ll, lh, hl, hh, out, n_groups);
}

// Round 2
// 428.931 us; speedup vs baseline: 1.0210x; 1.0210x over previous
//
#include <hip/hip_runtime.h>

// Inverse 2D Haar DWT (pywt idwt2, 'haar').
// Input:  ll/lh/hl/hh, each (B,C,H,W) = (4,64,256,256) fp32.
// Output: (B,C,2H,2W) fp32.
// Per input coeff (h,w):
//   out[2h,  2w]   = (ll+lh+hl+hh)*0.5   (a)
//   out[2h,  2w+1] = (ll+lh-hl-hh)*0.5   (b)
//   out[2h+1,2w]   = (ll-lh+hl-hh)*0.5   (c)
//   out[2h+1,2w+1] = (ll-lh-hl+hh)*0.5   (d)
//
// Mapping: one thread per output float4 slot s of one input row.
//   - loads: float2 at ((float2*)in)[idx] from each input (cols 2s, 2s+1)
//     -> globally contiguous, 512 B per wave-instruction, perfectly coalesced
//   - stores: one float4 per output row (rows 2r and 2r+1), consecutive lanes
//     -> consecutive float4 slots: 1 KiB fully-dense contiguous wave stores
// (Previous version had lane-strided stores: each store instruction only
//  half-filled its 64 B segments -> 2x store transactions.)

#define W_IN 256           // input width
#define H_IN 256           // input height
#define SLOTS 128          // output float4 slots per output row (2*W_IN/4)

__global__ __launch_bounds__(256) void idwt2_haar_kernel(
    const float* __restrict__ ll, const float* __restrict__ lh,
    const float* __restrict__ hl, const float* __restrict__ hh,
    float* __restrict__ out, int n_threads) {
    int idx = blockIdx.x * blockDim.x + threadIdx.x;
    if (idx >= n_threads) return;

    int s       = idx & (SLOTS - 1);     // output float4 slot within row
    int rowflat = idx >> 7;              // flat input row index in [0, B*C*H)
    int r       = rowflat & (H_IN - 1);  // row within image
    int img     = rowflat >> 8;          // image index in [0, B*C)

    // float2 index == idx (rowflat*128 + s): cols 2s, 2s+1 of this input row
    const float2 vll = ((const float2*)ll)[idx];
    const float2 vlh = ((const float2*)lh)[idx];
    const float2 vhl = ((const float2*)hl)[idx];
    const float2 vhh = ((const float2*)hh)[idx];

    float4 r0, r1;
    // input col 2s
    {
        float s01 = vll.x + vlh.x, d01 = vll.x - vlh.x;
        float s23 = vhl.x + vhh.x, d23 = vhl.x - vhh.x;
        r0.x = 0.5f * (s01 + s23);  // a
        r0.y = 0.5f * (s01 - s23);  // b
        r1.x = 0.5f * (d01 + d23);  // c
        r1.y = 0.5f * (d01 - d23);  // d
    }
    // input col 2s+1
    {
        float s01 = vll.y + vlh.y, d01 = vll.y - vlh.y;
        float s23 = vhl.y + vhh.y, d23 = vhl.y - vhh.y;
        r0.z = 0.5f * (s01 + s23);
        r0.w = 0.5f * (s01 - s23);
        r1.z = 0.5f * (d01 + d23);
        r1.w = 0.5f * (d01 - d23);
    }

    // Output float4 base: even row = img*512 + 2r, odd row = +1 (in rows),
    // each output row is SLOTS float4s.
    long long base0 = ((long long)((img << 9) + (r << 1))) * SLOTS + s;
    float4* out4 = (float4*)out;
    out4[base0]         = r0;   // row 2r
    out4[base0 + SLOTS] = r1;   // row 2r+1
}

extern "C" void kernel_launch(void* const* d_in, const int* in_sizes, int n_in,
                              void* d_out, int out_size, void* d_ws, size_t ws_size,
                              hipStream_t stream) {
    const float* ll = (const float*)d_in[0];
    const float* lh = (const float*)d_in[1];
    const float* hl = (const float*)d_in[2];
    const float* hh = (const float*)d_in[3];
    float* out = (float*)d_out;

    int n = in_sizes[0];           // 16,777,216 elements per input
    int n_threads = n / 2;         // one thread per 2 input cols = 8,388,608
    int block = 256;
    int grid = (n_threads + block - 1) / block;

    idwt2_haar_kernel<<<grid, block, 0, stream>>>(ll, lh, hl, hh, out, n_threads);
}